// Round 4
// baseline (1638.572 us; speedup 1.0000x reference)
//
#include <hip/hip_runtime.h>
#include <cstddef>

#define NE 16384
#define NN 4096
#define BG 16

__device__ __forceinline__ float lrelu(float v){ return v >= 0.f ? v : 0.01f*v; }
__device__ __forceinline__ float sigm(float v){ return 1.f/(1.f + expf(-v)); }

// ---------------- setup: Bp (f-major We2), B_smT, WihT, h0, he, deg, cnt ----------------
__global__ __launch_bounds__(256) void setup_kernel(
    const float* __restrict__ x, const float* __restrict__ ea,
    const int* __restrict__ ei,
    const float* __restrict__ W0, const float* __restrict__ b0,
    const float* __restrict__ We1, const float* __restrict__ be1,
    const float* __restrict__ We2, const float* __restrict__ be2,
    const float* __restrict__ root, const float* __restrict__ Whh,
    const float* __restrict__ Wih,
    float* __restrict__ Bp, float* __restrict__ BsmT, float* __restrict__ WihT,
    float* __restrict__ h, float* __restrict__ he,
    int* __restrict__ deg, int* __restrict__ cnt, float* __restrict__ agg)
{
    int t = blockIdx.x*256 + threadIdx.x;   // grid: 4096x256 = 1,048,576 = NE*64
    {   // he: [E,64]  lrelu(edge_attr @ We1 + be1)
        int e = t >> 6, f = t & 63;
        float v = be1[f];
        #pragma unroll
        for (int d = 0; d < 4; ++d) v += ea[e*4+d]*We1[d*64+f];
        he[t] = lrelu(v);
    }
    if (t < NN*64) {    // h0 = lrelu(x @ W0 + b0); zero agg
        int n = t >> 6, f = t & 63;
        float v = b0[f];
        #pragma unroll
        for (int d = 0; d < 3; ++d) v += x[n*3+d]*W0[d*64+f];
        h[t] = lrelu(v);
        agg[t] = 0.f;
    }
    if (t < 64*4096) {  // Bp[d][f*64+k] = We2[k][d*64+f]  (f-major B for fused GEMM)
        int d = t >> 12, r = t & 4095;
        int f = r >> 6, k = r & 63;
        Bp[t] = We2[(size_t)k*4096 + d*64 + f];
    }
    if (t < 320*64) {   // BsmT[c][d]: c<64 bias(be2), 64..255 gh(Whh), 256.. mroot(root)
        int c = t >> 6, d = t & 63;
        float v;
        if (c < 64)       v = be2[d*64 + c];
        else if (c < 256) v = Whh[(c-64)*64 + d];
        else              v = root[d*64 + (c-256)];
        BsmT[t] = v;
    }
    if (t < 12288) { int k = t / 192; WihT[t] = Wih[(t - k*192)*64 + k]; }  // WihT[k][g]
    if (t < NE) {
        atomicAdd(&deg[ei[NE + t]], 1);   // in-degree (dst) for mean aggr
        atomicAdd(&cnt[ei[t]], 1);        // out-degree (src) for edge sort
    }
}

// ---------------- exclusive scan of cnt[4096] -> offs[4097] (1 block) ----------------
__global__ __launch_bounds__(256) void scan_kernel(const int* __restrict__ cnt,
                                                   int* __restrict__ offs)
{
    __shared__ int ps[256];
    int t = threadIdx.x;
    int base = t*16;
    int loc[16];
    int s = 0;
    #pragma unroll
    for (int i = 0; i < 16; ++i) { loc[i] = s; s += cnt[base+i]; }
    ps[t] = s; __syncthreads();
    for (int off = 1; off < 256; off <<= 1) {
        int v = 0;
        if (t >= off) v = ps[t-off];
        __syncthreads();
        if (t >= off) ps[t] += v;
        __syncthreads();
    }
    int pre = (t == 0) ? 0 : ps[t-1];
    #pragma unroll
    for (int i = 0; i < 16; ++i) offs[base+i] = pre + loc[i];
    if (t == 255) offs[NN] = pre + s;
}

// ---------------- scatter: build src-sorted edge arrays ----------------
__global__ __launch_bounds__(256) void scatter_kernel(
    const int* __restrict__ ei, const int* __restrict__ offs,
    int* __restrict__ cnt,  // consumed as cursor via atomicSub
    int* __restrict__ srcs, int* __restrict__ dsts, int* __restrict__ perm)
{
    int e = blockIdx.x*256 + threadIdx.x;
    if (e >= NE) return;
    int s = ei[e], d = ei[NE + e];
    int old = atomicSub(&cnt[s], 1);
    int pos = offs[s] + old - 1;
    srcs[pos] = s; dsts[pos] = d; perm[pos] = e;
}

// ---------------- permute he into sorted-edge order (one-time) ----------------
__global__ __launch_bounds__(256) void heperm_kernel(
    const float* __restrict__ he, const int* __restrict__ perm,
    float* __restrict__ he_s)
{
    int t = blockIdx.x*256 + threadIdx.x;   // NE*64 threads
    int pos = t >> 6, f = t & 63;
    he_s[t] = he[(size_t)perm[pos]*64 + f];
}

// ---------------- inv_deg + per-graph node ranges ----------------
__global__ __launch_bounds__(256) void inv_range_kernel(
    const int* __restrict__ deg, const int* __restrict__ batch,
    float* __restrict__ inv_deg, int* __restrict__ gstart, int* __restrict__ gend)
{
    int n = blockIdx.x*256 + threadIdx.x;
    if (n >= NN) return;
    inv_deg[n] = 1.f / fmaxf((float)deg[n], 1.f);
    int b  = batch[n];
    int bp = (n == 0)    ? -1 : batch[n-1];
    int bn = (n == NN-1) ? BG : batch[n+1];
    for (int g = bp+1; g <= b; ++g) gstart[g] = n;
    for (int g = b;   g <  bn; ++g) gend[g]   = n+1;
    if (n == 0)    for (int g = 0;   g < b;  ++g) gend[g]   = 0;
    if (n == NN-1) for (int g = b+1; g < BG; ++g) gstart[g] = NN;
}

// ---------------- per-iter small GEMM: Csm[4096][320] = h @ BsmT^T ----------------
// cols: [bias(be2):64][gh r,z,n:192][mroot:64]
__global__ __launch_bounds__(256) void csm_gemm(
    const float* __restrict__ h, const float* __restrict__ BsmT,
    float* __restrict__ Csm)
{
    __shared__ float ht[16][64];
    int t = threadIdx.x;
    int n0 = blockIdx.x * 16;
    #pragma unroll
    for (int i = 0; i < 4; ++i) {
        int idx = t + i*256;
        ht[idx>>6][idx&63] = h[(size_t)n0*64 + idx];
    }
    __syncthreads();
    for (int idx = t; idx < 16*320; idx += 256) {
        int r = idx / 320, c = idx - r*320;
        const float* bt = BsmT + (size_t)c*64;
        const float* hr = ht[r];
        float s = 0.f;
        #pragma unroll 8
        for (int d = 0; d < 64; d += 4) {
            float4 a = *(const float4*)(hr + d);
            float4 b = *(const float4*)(bt + d);
            s += a.x*b.x + a.y*b.y + a.z*b.z + a.w*b.w;
        }
        Csm[(size_t)(n0+r)*320 + c] = s;
    }
}

// ---------------- fused: G-tile GEMM (LDS) + edge contraction + scatter ----------------
// grid (32 f-pairs, 32 node-tiles) x 256 thr. Block computes
// G[m0..m0+128)[f0,f0+1][all 64 k] via register GEMM, dumps to LDS (64 KB,
// overlaid on the As staging buffer), then half-wave-per-edge contracts
// msg[e,f] = sum_k he[e,k]*G[src][f][k] + bias[src,f] -> one atomic per (e,f).
__global__ __launch_bounds__(256) void fused_msg(
    const float* __restrict__ h, const float* __restrict__ Bp,
    const float* __restrict__ he_s, const float* __restrict__ Csm,
    const int* __restrict__ offs, const int* __restrict__ srcs,
    const int* __restrict__ dsts, float* __restrict__ agg)
{
    __shared__ float buf[128*128];   // 64 KB; As[64][132] (33 KB) overlays, then G[128][128]
    int t = threadIdx.x;
    int bx = blockIdx.x;             // f-pair tile 0..31 (f0 = 2*bx)
    int by = blockIdx.y;             // node tile 0..31
    int m0 = by*128, c0 = bx*128;

    {   // stage A^T with XOR swizzle col = r ^ 4*(tx&7): 2-way (free) bank pattern
        float (*As)[132] = (float(*)[132])buf;
        #pragma unroll
        for (int i = 0; i < 8; ++i) {
            int idx4 = t + i*256;
            int r  = idx4 >> 4;
            int kc = (idx4 & 15) * 4;
            float4 v = *(const float4*)(h + (size_t)(m0 + r)*64 + kc);
            int cs = r ^ ((idx4 & 7) * 4);
            As[kc+0][cs] = v.x; As[kc+1][cs] = v.y;
            As[kc+2][cs] = v.z; As[kc+3][cs] = v.w;
        }
    }
    __syncthreads();

    int tx = t & 15, ty = t >> 4;
    float acc[8][8];
    #pragma unroll
    for (int i = 0; i < 8; ++i)
        #pragma unroll
        for (int j = 0; j < 8; ++j) acc[i][j] = 0.f;

    {
        const float (*As)[132] = (const float(*)[132])buf;
        #pragma unroll 8
        for (int k = 0; k < 64; ++k) {
            int sw = ((k >> 2) & 7) * 4;
            float4 a0 = *(const float4*)&As[k][(ty*4) ^ sw];
            float4 a1 = *(const float4*)&As[k][64 + ((ty*4) ^ sw)];
            const float* bk = Bp + (size_t)k*4096 + c0 + tx*4;
            float4 b0 = *(const float4*)bk;
            float4 b1 = *(const float4*)(bk + 64);
            float av[8] = {a0.x,a0.y,a0.z,a0.w,a1.x,a1.y,a1.z,a1.w};
            float bv[8] = {b0.x,b0.y,b0.z,b0.w,b1.x,b1.y,b1.z,b1.w};
            #pragma unroll
            for (int i = 0; i < 8; ++i)
                #pragma unroll
                for (int j = 0; j < 8; ++j) acc[i][j] += av[i]*bv[j];
        }
    }
    __syncthreads();   // all As reads done; reuse buf as G

    float (*G)[128] = (float(*)[128])buf;
    #pragma unroll
    for (int i = 0; i < 8; ++i) {
        int m = (i>>2)*64 + ty*4 + (i&3);
        *(float4*)&G[m][tx*4]      = make_float4(acc[i][0],acc[i][1],acc[i][2],acc[i][3]);
        *(float4*)&G[m][64+tx*4]   = make_float4(acc[i][4],acc[i][5],acc[i][6],acc[i][7]);
    }
    __syncthreads();

    // Edge phase: half-wave per edge; full k=64 reduction in-block.
    int w = t >> 6, lane = t & 63;
    int hf = lane >> 5, j = lane & 31;
    int kk = j*2;
    int est  = offs[m0];
    int eend = offs[m0+128];
    int f0 = bx*2;
    for (int e = est + w*2 + hf; e < eend; e += 8) {
        int src = srcs[e], dst = dsts[e];
        int sl = src - m0;
        float2 hv = *(const float2*)(he_s + (size_t)e*64 + kk);
        float2 g0 = *(const float2*)&G[sl][kk];
        float2 g1 = *(const float2*)&G[sl][64 + kk];
        float p0 = hv.x*g0.x + hv.y*g0.y;
        float p1 = hv.x*g1.x + hv.y*g1.y;
        #pragma unroll
        for (int o = 16; o >= 1; o >>= 1) {
            p0 += __shfl_xor(p0, o);
            p1 += __shfl_xor(p1, o);
        }
        if (j == 0) atomicAdd(&agg[(size_t)dst*64 + f0],
                              p0 + Csm[(size_t)src*320 + f0]);
        if (j == 1) atomicAdd(&agg[(size_t)dst*64 + f0 + 1],
                              p1 + Csm[(size_t)src*320 + f0 + 1]);
    }
}

// ---------------- node kernel: m -> gi GEMM -> GRU (in-place h); zeros agg ----
__global__ __launch_bounds__(256) void node_kernel(
    const float* __restrict__ Csm, float* __restrict__ agg,
    const float* __restrict__ inv_deg, const float* __restrict__ conv_b,
    const float* __restrict__ WihT, const float* __restrict__ bih,
    const float* __restrict__ bhh, float* __restrict__ h)
{
    __shared__ float WT[64][196];   // WihT[k][g]
    __shared__ float mT[64][18];    // m transposed [d][node]
    int t = threadIdx.x;
    int n0 = blockIdx.x * 16;
    #pragma unroll
    for (int i = 0; i < 48; ++i) {  // stage WihT (12288)
        int idx = t + i*256;
        int k = idx / 192;
        WT[k][idx - k*192] = WihT[idx];
    }
    #pragma unroll
    for (int i = 0; i < 4; ++i) {   // m = lrelu(agg*inv + mroot + conv_b); zero agg
        int idx = t + i*256;
        int n = idx >> 6, dd = idx & 63;
        int gn = n0 + n;
        float av = agg[(size_t)gn*64 + dd];
        agg[(size_t)gn*64 + dd] = 0.f;   // ready for next iteration
        float mr = Csm[(size_t)gn*320 + 256 + dd];
        mT[dd][n] = lrelu(av*inv_deg[gn] + mr + conv_b[dd]);
    }
    __syncthreads();

    int tx = t & 31, ty = t >> 5;   // tx: gate pair, ty: node pair
    float acc[2][2][3] = {};
    for (int k = 0; k < 64; ++k) {
        float2 a  = *(float2*)&mT[k][ty*2];
        float2 br = *(float2*)&WT[k][tx*2];
        float2 bz = *(float2*)&WT[k][64 + tx*2];
        float2 bn = *(float2*)&WT[k][128 + tx*2];
        acc[0][0][0] += a.x*br.x; acc[0][1][0] += a.x*br.y;
        acc[1][0][0] += a.y*br.x; acc[1][1][0] += a.y*br.y;
        acc[0][0][1] += a.x*bz.x; acc[0][1][1] += a.x*bz.y;
        acc[1][0][1] += a.y*bz.x; acc[1][1][1] += a.y*bz.y;
        acc[0][0][2] += a.x*bn.x; acc[0][1][2] += a.x*bn.y;
        acc[1][0][2] += a.y*bn.x; acc[1][1][2] += a.y*bn.y;
    }
    #pragma unroll
    for (int i = 0; i < 2; ++i) {
        int n = n0 + ty*2 + i;
        const float* Cn = Csm + (size_t)n*320;
        #pragma unroll
        for (int j = 0; j < 2; ++j) {
            int g = tx*2 + j;
            float r  = sigm(acc[i][j][0] + bih[g]     + Cn[64  + g] + bhh[g]);
            float z  = sigm(acc[i][j][1] + bih[64+g]  + Cn[128 + g] + bhh[64+g]);
            float nn = tanhf(acc[i][j][2] + bih[128+g] + r*(Cn[192 + g] + bhh[128+g]));
            float ho = h[(size_t)n*64 + g];
            h[(size_t)n*64 + g] = (1.f - z)*nn + z*ho;
        }
    }
}

// ---------------- finale ----------------
__device__ __forceinline__ float q_val(const float* lbih, const float* lbhh, int g)
{
    float gi = lbih[g]     + lbhh[g];
    float gg = lbih[128+g] + lbhh[128+g];
    float go = lbih[192+g] + lbhh[192+g];
    return sigm(go)*tanhf(sigm(gi)*tanhf(gg));   // hl0=cl0=q_star0=0
}

__global__ __launch_bounds__(256) void e_kernel(
    const float* __restrict__ h, const float* __restrict__ lbih,
    const float* __restrict__ lbhh, float* __restrict__ e)
{
    __shared__ float qs[64];
    int t = threadIdx.x;
    if (t < 64) qs[t] = q_val(lbih, lbhh, t);
    __syncthreads();
    int w = t >> 6, f = t & 63;
    int n = blockIdx.x*4 + w;
    float p = h[(size_t)n*64 + f]*qs[f];
    #pragma unroll
    for (int off = 32; off; off >>= 1) p += __shfl_xor(p, off);
    if (f == 0) e[n] = p;
}

__global__ __launch_bounds__(1024) void pool_kernel(
    const float* __restrict__ h, float* __restrict__ e,
    const int* __restrict__ gstart, const int* __restrict__ gend,
    const float* __restrict__ lbih, const float* __restrict__ lbhh,
    const float* __restrict__ Wout, const float* __restrict__ bout,
    float* __restrict__ out)
{
    __shared__ float red[1024];
    __shared__ float rp[64];
    __shared__ float sval;
    int g = blockIdx.x, t = threadIdx.x;
    int s = gstart[g], en = gend[g];

    float mx = -1e30f;
    for (int n = s+t; n < en; n += 1024) mx = fmaxf(mx, e[n]);
    red[t] = mx; __syncthreads();
    for (int st = 512; st; st >>= 1) { if (t < st) red[t] = fmaxf(red[t], red[t+st]); __syncthreads(); }
    if (t == 0) sval = red[0];
    __syncthreads();
    float lmx = sval;
    __syncthreads();

    float sm = 0.f;
    for (int n = s+t; n < en; n += 1024) { float a = expf(e[n]-lmx); e[n] = a; sm += a; }
    red[t] = sm; __syncthreads();
    for (int st = 512; st; st >>= 1) { if (t < st) red[t] += red[t+st]; __syncthreads(); }
    if (t == 0) sval = (red[0] > 0.f) ? 1.f/red[0] : 0.f;
    __syncthreads();
    float inv_asum = sval;
    __syncthreads();

    int w = t >> 6, f = t & 63;
    float racc = 0.f;
    for (int n = s+w; n < en; n += 16) racc += e[n]*h[(size_t)n*64 + f];
    red[t] = racc; __syncthreads();
    if (w == 0) {
        float a = 0.f;
        #pragma unroll
        for (int i = 0; i < 16; ++i) a += red[i*64 + f];
        rp[f] = a*inv_asum;
    }
    __syncthreads();

    if (t < 64) {
        float qv = q_val(lbih, lbhh, t);
        float p0 = qv*Wout[t*2]   + rp[t]*Wout[(64+t)*2];
        float p1 = qv*Wout[t*2+1] + rp[t]*Wout[(64+t)*2+1];
        #pragma unroll
        for (int off = 32; off; off >>= 1) { p0 += __shfl_xor(p0, off); p1 += __shfl_xor(p1, off); }
        if (t == 0) { out[g*2] = p0 + bout[0]; out[g*2+1] = p1 + bout[1]; }
    }
}

extern "C" void kernel_launch(void* const* d_in, const int* in_sizes, int n_in,
                              void* d_out, int out_size, void* d_ws, size_t ws_size,
                              hipStream_t stream)
{
    const float* x      = (const float*)d_in[0];
    const float* ea     = (const float*)d_in[1];
    const int*   ei     = (const int*)  d_in[2];
    const int*   batch  = (const int*)  d_in[3];
    const float* W0     = (const float*)d_in[4];
    const float* b0     = (const float*)d_in[5];
    const float* We1    = (const float*)d_in[6];
    const float* be1    = (const float*)d_in[7];
    const float* We2    = (const float*)d_in[8];
    const float* be2    = (const float*)d_in[9];
    const float* root   = (const float*)d_in[10];
    const float* conv_b = (const float*)d_in[11];
    const float* Wih    = (const float*)d_in[12];
    const float* Whh    = (const float*)d_in[13];
    const float* bih    = (const float*)d_in[14];
    const float* bhh    = (const float*)d_in[15];
    const float* lbih   = (const float*)d_in[18];
    const float* lbhh   = (const float*)d_in[19];
    const float* Wout   = (const float*)d_in[20];
    const float* bout   = (const float*)d_in[21];
    float* out = (float*)d_out;

    float* W = (float*)d_ws;
    size_t off = 0;
    float* h       = W + off; off += (size_t)NN*64;
    float* he      = W + off; off += (size_t)NE*64;
    float* he_s    = W + off; off += (size_t)NE*64;
    float* agg     = W + off; off += (size_t)NN*64;
    float* Bp      = W + off; off += (size_t)64*4096;
    float* BsmT    = W + off; off += 320*64;
    float* Csm     = W + off; off += (size_t)NN*320;
    float* WihT    = W + off; off += 12288;
    float* inv_deg = W + off; off += NN;
    float* e       = W + off; off += NN;
    int*   deg     = (int*)(W + off); off += NN;   // deg+cnt contiguous: one memset
    int*   cnt     = (int*)(W + off); off += NN;
    int*   offs    = (int*)(W + off); off += NN+1;
    int*   srcs    = (int*)(W + off); off += NE;
    int*   dsts    = (int*)(W + off); off += NE;
    int*   perm    = (int*)(W + off); off += NE;
    int*   gstart  = (int*)(W + off); off += BG;
    int*   gend    = (int*)(W + off); off += BG;

    hipMemsetAsync(deg, 0, 2*NN*sizeof(int), stream);
    setup_kernel<<<4096, 256, 0, stream>>>(x, ea, ei, W0, b0, We1, be1, We2, be2,
                                           root, Whh, Wih, Bp, BsmT, WihT,
                                           h, he, deg, cnt, agg);
    scan_kernel<<<1, 256, 0, stream>>>(cnt, offs);
    scatter_kernel<<<64, 256, 0, stream>>>(ei, offs, cnt, srcs, dsts, perm);
    heperm_kernel<<<4096, 256, 0, stream>>>(he, perm, he_s);
    inv_range_kernel<<<16, 256, 0, stream>>>(deg, batch, inv_deg, gstart, gend);

    for (int it = 0; it < 6; ++it) {
        csm_gemm<<<NN/16, 256, 0, stream>>>(h, BsmT, Csm);
        fused_msg<<<dim3(32, 32), 256, 0, stream>>>(h, Bp, he_s, Csm,
                                                    offs, srcs, dsts, agg);
        node_kernel<<<NN/16, 256, 0, stream>>>(Csm, agg, inv_deg, conv_b,
                                               WihT, bih, bhh, h);
    }

    e_kernel<<<NN/4, 256, 0, stream>>>(h, lbih, lbhh, e);
    pool_kernel<<<BG, 1024, 0, stream>>>(h, e, gstart, gend, lbih, lbhh, Wout, bout, out);
}

// Round 5
// 824.985 us; speedup vs baseline: 1.9862x; 1.9862x over previous
//
#include <hip/hip_runtime.h>
#include <cstddef>

#define NE 16384
#define NN 4096
#define BG 16

__device__ __forceinline__ float lrelu(float v){ return v >= 0.f ? v : 0.01f*v; }
__device__ __forceinline__ float sigm(float v){ return 1.f/(1.f + expf(-v)); }
__device__ __forceinline__ float rl(float v, int l){
    return __int_as_float(__builtin_amdgcn_readlane(__float_as_int(v), l));
}

// ---------------- setup: Bp2 (permuted We2), BsmT, WihT, h0, he, deg, cnt ----------------
__global__ __launch_bounds__(256) void setup_kernel(
    const float* __restrict__ x, const float* __restrict__ ea,
    const int* __restrict__ ei,
    const float* __restrict__ W0, const float* __restrict__ b0,
    const float* __restrict__ We1, const float* __restrict__ be1,
    const float* __restrict__ We2, const float* __restrict__ be2,
    const float* __restrict__ root, const float* __restrict__ Whh,
    const float* __restrict__ Wih,
    float* __restrict__ Bp2, float* __restrict__ BsmT, float* __restrict__ WihT,
    float* __restrict__ h, float* __restrict__ he,
    int* __restrict__ deg, int* __restrict__ cnt, float* __restrict__ agg)
{
    int t = blockIdx.x*256 + threadIdx.x;   // grid: 4096x256 = 1,048,576 = NE*64
    {   // he: [E,64]  lrelu(edge_attr @ We1 + be1)
        int e = t >> 6, f = t & 63;
        float v = be1[f];
        #pragma unroll
        for (int d = 0; d < 4; ++d) v += ea[e*4+d]*We1[d*64+f];
        he[t] = lrelu(v);
    }
    if (t < NN*64) {    // h0 = lrelu(x @ W0 + b0); zero agg
        int n = t >> 6, f = t & 63;
        float v = b0[f];
        #pragma unroll
        for (int d = 0; d < 3; ++d) v += x[n*3+d]*W0[d*64+f];
        h[t] = lrelu(v);
        agg[t] = 0.f;
    }
    if (t < 64*4096) {  // Bp2[d][k*64+f] = We2[k][d*64+f]
        int d = t >> 12, c = t & 4095;
        int k = c >> 6, f = c & 63;
        Bp2[t] = We2[(size_t)k*4096 + d*64 + f];
    }
    if (t < 320*64) {   // BsmT[c][d]: c<64 bias(be2), 64..255 gh(Whh), 256.. mroot(root)
        int c = t >> 6, d = t & 63;
        float v;
        if (c < 64)       v = be2[d*64 + c];
        else if (c < 256) v = Whh[(c-64)*64 + d];
        else              v = root[d*64 + (c-256)];
        BsmT[t] = v;
    }
    if (t < 12288) { int k = t / 192; WihT[t] = Wih[(t - k*192)*64 + k]; }  // WihT[k][g]
    if (t < NE) {
        atomicAdd(&deg[ei[NE + t]], 1);   // in-degree (dst) for mean aggr
        atomicAdd(&cnt[ei[t]], 1);        // out-degree (src) for edge sort
    }
}

// ---------------- exclusive scan of cnt[4096] -> offs[4097] (1 block) ----------------
__global__ __launch_bounds__(256) void scan_kernel(const int* __restrict__ cnt,
                                                   int* __restrict__ offs)
{
    __shared__ int ps[256];
    int t = threadIdx.x;
    int base = t*16;
    int loc[16];
    int s = 0;
    #pragma unroll
    for (int i = 0; i < 16; ++i) { loc[i] = s; s += cnt[base+i]; }
    ps[t] = s; __syncthreads();
    for (int off = 1; off < 256; off <<= 1) {
        int v = 0;
        if (t >= off) v = ps[t-off];
        __syncthreads();
        if (t >= off) ps[t] += v;
        __syncthreads();
    }
    int pre = (t == 0) ? 0 : ps[t-1];
    #pragma unroll
    for (int i = 0; i < 16; ++i) offs[base+i] = pre + loc[i];
    if (t == 255) offs[NN] = pre + s;
}

// ---------------- scatter: build src-sorted edge arrays ----------------
__global__ __launch_bounds__(256) void scatter_kernel(
    const int* __restrict__ ei, const int* __restrict__ offs,
    int* __restrict__ cnt,  // consumed as cursor via atomicSub
    int* __restrict__ srcs, int* __restrict__ dsts, int* __restrict__ perm)
{
    int e = blockIdx.x*256 + threadIdx.x;
    if (e >= NE) return;
    int s = ei[e], d = ei[NE + e];
    int old = atomicSub(&cnt[s], 1);
    int pos = offs[s] + old - 1;
    srcs[pos] = s; dsts[pos] = d; perm[pos] = e;
}

// ---------------- permute he into sorted-edge order (one-time) ----------------
__global__ __launch_bounds__(256) void heperm_kernel(
    const float* __restrict__ he, const int* __restrict__ perm,
    float* __restrict__ he_s)
{
    int t = blockIdx.x*256 + threadIdx.x;   // NE*64 threads
    int pos = t >> 6, f = t & 63;
    he_s[t] = he[(size_t)perm[pos]*64 + f];
}

// ---------------- inv_deg + per-graph node ranges ----------------
__global__ __launch_bounds__(256) void inv_range_kernel(
    const int* __restrict__ deg, const int* __restrict__ batch,
    float* __restrict__ inv_deg, int* __restrict__ gstart, int* __restrict__ gend)
{
    int n = blockIdx.x*256 + threadIdx.x;
    if (n >= NN) return;
    inv_deg[n] = 1.f / fmaxf((float)deg[n], 1.f);
    int b  = batch[n];
    int bp = (n == 0)    ? -1 : batch[n-1];
    int bn = (n == NN-1) ? BG : batch[n+1];
    for (int g = bp+1; g <= b; ++g) gstart[g] = n;
    for (int g = b;   g <  bn; ++g) gend[g]   = n+1;
    if (n == 0)    for (int g = 0;   g < b;  ++g) gend[g]   = 0;
    if (n == NN-1) for (int g = b+1; g < BG; ++g) gstart[g] = NN;
}

// ---------------- per-iter small GEMM: Csm[4096][320] = h @ BsmT^T ----------------
// cols: [bias(be2):64][gh r,z,n:192][mroot:64]
__global__ __launch_bounds__(256) void csm_gemm(
    const float* __restrict__ h, const float* __restrict__ BsmT,
    float* __restrict__ Csm)
{
    __shared__ float ht[16][64];
    int t = threadIdx.x;
    int n0 = blockIdx.x * 16;
    #pragma unroll
    for (int i = 0; i < 4; ++i) {
        int idx = t + i*256;
        ht[idx>>6][idx&63] = h[(size_t)n0*64 + idx];
    }
    __syncthreads();
    for (int idx = t; idx < 16*320; idx += 256) {
        int r = idx / 320, c = idx - r*320;
        const float* bt = BsmT + (size_t)c*64;
        const float* hr = ht[r];
        float s = 0.f;
        #pragma unroll 8
        for (int d = 0; d < 64; d += 4) {
            float4 a = *(const float4*)(hr + d);
            float4 b = *(const float4*)(bt + d);
            s += a.x*b.x + a.y*b.y + a.z*b.z + a.w*b.w;
        }
        Csm[(size_t)(n0+r)*320 + c] = s;
    }
}

// ---------------- fused: per-4-node G in LDS + edge contraction ----------------
// Block owns 4 src nodes: computes G[4][64k][64f] (exactly 64 KB LDS) via
// register GEMM (acc[4][16], static), then wave-per-edge: lane=f, serial
// k-loop with readlane(he) broadcast, ONE atomic per (edge,f).
__global__ __launch_bounds__(256) void fused_msg(
    const float* __restrict__ h, const float* __restrict__ Bp2,
    const float* __restrict__ he_s, const float* __restrict__ Csm,
    const int* __restrict__ offs, const int* __restrict__ srcs,
    const int* __restrict__ dsts, float* __restrict__ agg)
{
    __shared__ float buf[16384];   // 64 KB: A[256] overlay, then G[4][4096]
    int t = threadIdx.x;
    int n0 = blockIdx.x * 4;

    if (t < 256) buf[t] = h[(size_t)n0*64 + t];   // A: buf[n*64+d]
    __syncthreads();

    // GEMM: acc[n][i*4+j] = G[n][c], c = i*1024 + t*4 + j
    float acc[4][16];
    #pragma unroll
    for (int n = 0; n < 4; ++n)
        #pragma unroll
        for (int j = 0; j < 16; ++j) acc[n][j] = 0.f;

    const float* bp = Bp2 + t*4;
    #pragma unroll 4
    for (int d = 0; d < 64; ++d) {
        float4 b0 = *(const float4*)(bp + (size_t)d*4096);
        float4 b1 = *(const float4*)(bp + (size_t)d*4096 + 1024);
        float4 b2 = *(const float4*)(bp + (size_t)d*4096 + 2048);
        float4 b3 = *(const float4*)(bp + (size_t)d*4096 + 3072);
        #pragma unroll
        for (int n = 0; n < 4; ++n) {
            float av = buf[n*64 + d];
            acc[n][0]  += av*b0.x; acc[n][1]  += av*b0.y;
            acc[n][2]  += av*b0.z; acc[n][3]  += av*b0.w;
            acc[n][4]  += av*b1.x; acc[n][5]  += av*b1.y;
            acc[n][6]  += av*b1.z; acc[n][7]  += av*b1.w;
            acc[n][8]  += av*b2.x; acc[n][9]  += av*b2.y;
            acc[n][10] += av*b2.z; acc[n][11] += av*b2.w;
            acc[n][12] += av*b3.x; acc[n][13] += av*b3.y;
            acc[n][14] += av*b3.z; acc[n][15] += av*b3.w;
        }
    }
    __syncthreads();   // all A reads done; overwrite buf with G

    #pragma unroll
    for (int n = 0; n < 4; ++n)
        #pragma unroll
        for (int i = 0; i < 4; ++i)
            *(float4*)&buf[n*4096 + i*1024 + t*4] =
                make_float4(acc[n][i*4+0], acc[n][i*4+1],
                            acc[n][i*4+2], acc[n][i*4+3]);
    __syncthreads();

    // Edge phase: wave per edge; lane = f.
    int w = t >> 6, lane = t & 63;
    int est  = offs[n0];
    int eend = offs[n0+4];
    for (int e = est + w; e < eend; e += 4) {
        int src = srcs[e], dst = dsts[e];
        int base = (src - n0) * 4096;
        float hv = he_s[(size_t)e*64 + lane];          // lane = k view
        float m0 = Csm[(size_t)src*320 + lane];        // bias[src, f=lane]
        float m1 = 0.f, m2 = 0.f, m3 = 0.f;
        #pragma unroll
        for (int k = 0; k < 64; k += 4) {
            m0 += rl(hv, k+0) * buf[base + (k+0)*64 + lane];
            m1 += rl(hv, k+1) * buf[base + (k+1)*64 + lane];
            m2 += rl(hv, k+2) * buf[base + (k+2)*64 + lane];
            m3 += rl(hv, k+3) * buf[base + (k+3)*64 + lane];
        }
        atomicAdd(&agg[(size_t)dst*64 + lane], (m0+m1)+(m2+m3));
    }
}

// ---------------- node kernel: m -> gi GEMM -> GRU (in-place h); zeros agg ----
__global__ __launch_bounds__(256) void node_kernel(
    const float* __restrict__ Csm, float* __restrict__ agg,
    const float* __restrict__ inv_deg, const float* __restrict__ conv_b,
    const float* __restrict__ WihT, const float* __restrict__ bih,
    const float* __restrict__ bhh, float* __restrict__ h)
{
    __shared__ float WT[64][196];   // WihT[k][g]
    __shared__ float mT[64][18];    // m transposed [d][node]
    int t = threadIdx.x;
    int n0 = blockIdx.x * 16;
    #pragma unroll
    for (int i = 0; i < 48; ++i) {  // stage WihT (12288)
        int idx = t + i*256;
        int k = idx / 192;
        WT[k][idx - k*192] = WihT[idx];
    }
    #pragma unroll
    for (int i = 0; i < 4; ++i) {   // m = lrelu(agg*inv + mroot + conv_b); zero agg
        int idx = t + i*256;
        int n = idx >> 6, dd = idx & 63;
        int gn = n0 + n;
        float av = agg[(size_t)gn*64 + dd];
        agg[(size_t)gn*64 + dd] = 0.f;   // ready for next iteration
        float mr = Csm[(size_t)gn*320 + 256 + dd];
        mT[dd][n] = lrelu(av*inv_deg[gn] + mr + conv_b[dd]);
    }
    __syncthreads();

    int tx = t & 31, ty = t >> 5;   // tx: gate pair, ty: node pair
    float acc[2][2][3] = {};
    for (int k = 0; k < 64; ++k) {
        float2 a  = *(float2*)&mT[k][ty*2];
        float2 br = *(float2*)&WT[k][tx*2];
        float2 bz = *(float2*)&WT[k][64 + tx*2];
        float2 bn = *(float2*)&WT[k][128 + tx*2];
        acc[0][0][0] += a.x*br.x; acc[0][1][0] += a.x*br.y;
        acc[1][0][0] += a.y*br.x; acc[1][1][0] += a.y*br.y;
        acc[0][0][1] += a.x*bz.x; acc[0][1][1] += a.x*bz.y;
        acc[1][0][1] += a.y*bz.x; acc[1][1][1] += a.y*bz.y;
        acc[0][0][2] += a.x*bn.x; acc[0][1][2] += a.x*bn.y;
        acc[1][0][2] += a.y*bn.x; acc[1][1][2] += a.y*bn.y;
    }
    #pragma unroll
    for (int i = 0; i < 2; ++i) {
        int n = n0 + ty*2 + i;
        const float* Cn = Csm + (size_t)n*320;
        #pragma unroll
        for (int j = 0; j < 2; ++j) {
            int g = tx*2 + j;
            float r  = sigm(acc[i][j][0] + bih[g]     + Cn[64  + g] + bhh[g]);
            float z  = sigm(acc[i][j][1] + bih[64+g]  + Cn[128 + g] + bhh[64+g]);
            float nn = tanhf(acc[i][j][2] + bih[128+g] + r*(Cn[192 + g] + bhh[128+g]));
            float ho = h[(size_t)n*64 + g];
            h[(size_t)n*64 + g] = (1.f - z)*nn + z*ho;
        }
    }
}

// ---------------- finale ----------------
__device__ __forceinline__ float q_val(const float* lbih, const float* lbhh, int g)
{
    float gi = lbih[g]     + lbhh[g];
    float gg = lbih[128+g] + lbhh[128+g];
    float go = lbih[192+g] + lbhh[192+g];
    return sigm(go)*tanhf(sigm(gi)*tanhf(gg));   // hl0=cl0=q_star0=0
}

__global__ __launch_bounds__(256) void e_kernel(
    const float* __restrict__ h, const float* __restrict__ lbih,
    const float* __restrict__ lbhh, float* __restrict__ e)
{
    __shared__ float qs[64];
    int t = threadIdx.x;
    if (t < 64) qs[t] = q_val(lbih, lbhh, t);
    __syncthreads();
    int w = t >> 6, f = t & 63;
    int n = blockIdx.x*4 + w;
    float p = h[(size_t)n*64 + f]*qs[f];
    #pragma unroll
    for (int off = 32; off; off >>= 1) p += __shfl_xor(p, off);
    if (f == 0) e[n] = p;
}

__global__ __launch_bounds__(1024) void pool_kernel(
    const float* __restrict__ h, float* __restrict__ e,
    const int* __restrict__ gstart, const int* __restrict__ gend,
    const float* __restrict__ lbih, const float* __restrict__ lbhh,
    const float* __restrict__ Wout, const float* __restrict__ bout,
    float* __restrict__ out)
{
    __shared__ float red[1024];
    __shared__ float rp[64];
    __shared__ float sval;
    int g = blockIdx.x, t = threadIdx.x;
    int s = gstart[g], en = gend[g];

    float mx = -1e30f;
    for (int n = s+t; n < en; n += 1024) mx = fmaxf(mx, e[n]);
    red[t] = mx; __syncthreads();
    for (int st = 512; st; st >>= 1) { if (t < st) red[t] = fmaxf(red[t], red[t+st]); __syncthreads(); }
    if (t == 0) sval = red[0];
    __syncthreads();
    float lmx = sval;
    __syncthreads();

    float sm = 0.f;
    for (int n = s+t; n < en; n += 1024) { float a = expf(e[n]-lmx); e[n] = a; sm += a; }
    red[t] = sm; __syncthreads();
    for (int st = 512; st; st >>= 1) { if (t < st) red[t] += red[t+st]; __syncthreads(); }
    if (t == 0) sval = (red[0] > 0.f) ? 1.f/red[0] : 0.f;
    __syncthreads();
    float inv_asum = sval;
    __syncthreads();

    int w = t >> 6, f = t & 63;
    float racc = 0.f;
    for (int n = s+w; n < en; n += 16) racc += e[n]*h[(size_t)n*64 + f];
    red[t] = racc; __syncthreads();
    if (w == 0) {
        float a = 0.f;
        #pragma unroll
        for (int i = 0; i < 16; ++i) a += red[i*64 + f];
        rp[f] = a*inv_asum;
    }
    __syncthreads();

    if (t < 64) {
        float qv = q_val(lbih, lbhh, t);
        float p0 = qv*Wout[t*2]   + rp[t]*Wout[(64+t)*2];
        float p1 = qv*Wout[t*2+1] + rp[t]*Wout[(64+t)*2+1];
        #pragma unroll
        for (int off = 32; off; off >>= 1) { p0 += __shfl_xor(p0, off); p1 += __shfl_xor(p1, off); }
        if (t == 0) { out[g*2] = p0 + bout[0]; out[g*2+1] = p1 + bout[1]; }
    }
}

extern "C" void kernel_launch(void* const* d_in, const int* in_sizes, int n_in,
                              void* d_out, int out_size, void* d_ws, size_t ws_size,
                              hipStream_t stream)
{
    const float* x      = (const float*)d_in[0];
    const float* ea     = (const float*)d_in[1];
    const int*   ei     = (const int*)  d_in[2];
    const int*   batch  = (const int*)  d_in[3];
    const float* W0     = (const float*)d_in[4];
    const float* b0     = (const float*)d_in[5];
    const float* We1    = (const float*)d_in[6];
    const float* be1    = (const float*)d_in[7];
    const float* We2    = (const float*)d_in[8];
    const float* be2    = (const float*)d_in[9];
    const float* root   = (const float*)d_in[10];
    const float* conv_b = (const float*)d_in[11];
    const float* Wih    = (const float*)d_in[12];
    const float* Whh    = (const float*)d_in[13];
    const float* bih    = (const float*)d_in[14];
    const float* bhh    = (const float*)d_in[15];
    const float* lbih   = (const float*)d_in[18];
    const float* lbhh   = (const float*)d_in[19];
    const float* Wout   = (const float*)d_in[20];
    const float* bout   = (const float*)d_in[21];
    float* out = (float*)d_out;

    float* W = (float*)d_ws;
    size_t off = 0;
    float* h       = W + off; off += (size_t)NN*64;
    float* he      = W + off; off += (size_t)NE*64;
    float* he_s    = W + off; off += (size_t)NE*64;
    float* agg     = W + off; off += (size_t)NN*64;
    float* Bp2     = W + off; off += (size_t)64*4096;
    float* BsmT    = W + off; off += 320*64;
    float* Csm     = W + off; off += (size_t)NN*320;
    float* WihT    = W + off; off += 12288;
    float* inv_deg = W + off; off += NN;
    float* e       = W + off; off += NN;
    int*   deg     = (int*)(W + off); off += NN;   // deg+cnt contiguous: one memset
    int*   cnt     = (int*)(W + off); off += NN;
    int*   offs    = (int*)(W + off); off += NN+1;
    int*   srcs    = (int*)(W + off); off += NE;
    int*   dsts    = (int*)(W + off); off += NE;
    int*   perm    = (int*)(W + off); off += NE;
    int*   gstart  = (int*)(W + off); off += BG;
    int*   gend    = (int*)(W + off); off += BG;

    hipMemsetAsync(deg, 0, 2*NN*sizeof(int), stream);
    setup_kernel<<<4096, 256, 0, stream>>>(x, ea, ei, W0, b0, We1, be1, We2, be2,
                                           root, Whh, Wih, Bp2, BsmT, WihT,
                                           h, he, deg, cnt, agg);
    scan_kernel<<<1, 256, 0, stream>>>(cnt, offs);
    scatter_kernel<<<64, 256, 0, stream>>>(ei, offs, cnt, srcs, dsts, perm);
    heperm_kernel<<<4096, 256, 0, stream>>>(he, perm, he_s);
    inv_range_kernel<<<16, 256, 0, stream>>>(deg, batch, inv_deg, gstart, gend);

    for (int it = 0; it < 6; ++it) {
        csm_gemm<<<NN/16, 256, 0, stream>>>(h, BsmT, Csm);
        fused_msg<<<NN/4, 256, 0, stream>>>(h, Bp2, he_s, Csm,
                                            offs, srcs, dsts, agg);
        node_kernel<<<NN/16, 256, 0, stream>>>(Csm, agg, inv_deg, conv_b,
                                               WihT, bih, bhh, h);
    }

    e_kernel<<<NN/4, 256, 0, stream>>>(h, lbih, lbhh, e);
    pool_kernel<<<BG, 1024, 0, stream>>>(h, e, gstart, gend, lbih, lbhh, Wout, bout, out);
}

// Round 7
// 752.753 us; speedup vs baseline: 2.1768x; 1.0960x over previous
//
#include <hip/hip_runtime.h>
#include <cstddef>

#define NE 16384
#define NN 4096
#define BG 16

__device__ __forceinline__ float lrelu(float v){ return v >= 0.f ? v : 0.01f*v; }
__device__ __forceinline__ float sigm(float v){ return 1.f/(1.f + expf(-v)); }
__device__ __forceinline__ float rl(float v, int l){
    return __int_as_float(__builtin_amdgcn_readlane(__float_as_int(v), l));
}

// ---------------- setup: Bp2 (permuted We2), BsmT, WihT, h0, he, deg, cnt ----------------
__global__ __launch_bounds__(256) void setup_kernel(
    const float* __restrict__ x, const float* __restrict__ ea,
    const int* __restrict__ ei,
    const float* __restrict__ W0, const float* __restrict__ b0,
    const float* __restrict__ We1, const float* __restrict__ be1,
    const float* __restrict__ We2, const float* __restrict__ be2,
    const float* __restrict__ root, const float* __restrict__ Whh,
    const float* __restrict__ Wih,
    float* __restrict__ Bp2, float* __restrict__ BsmT, float* __restrict__ WihT,
    float* __restrict__ h, float* __restrict__ he,
    int* __restrict__ deg, int* __restrict__ cnt, float* __restrict__ agg)
{
    int t = blockIdx.x*256 + threadIdx.x;   // grid: 4096x256 = 1,048,576 = NE*64
    {   // he: [E,64]  lrelu(edge_attr @ We1 + be1)
        int e = t >> 6, f = t & 63;
        float v = be1[f];
        #pragma unroll
        for (int d = 0; d < 4; ++d) v += ea[e*4+d]*We1[d*64+f];
        he[t] = lrelu(v);
    }
    if (t < NN*64) {    // h0 = lrelu(x @ W0 + b0); zero agg
        int n = t >> 6, f = t & 63;
        float v = b0[f];
        #pragma unroll
        for (int d = 0; d < 3; ++d) v += x[n*3+d]*W0[d*64+f];
        h[t] = lrelu(v);
        agg[t] = 0.f;
    }
    if (t < 64*4096) {  // Bp2[d][k*64+f] = We2[k][d*64+f]
        int d = t >> 12, c = t & 4095;
        int k = c >> 6, f = c & 63;
        Bp2[t] = We2[(size_t)k*4096 + d*64 + f];
    }
    if (t < 320*64) {   // BsmT[c][d]: c<64 bias(be2), 64..255 gh(Whh), 256.. mroot(root)
        int c = t >> 6, d = t & 63;
        float v;
        if (c < 64)       v = be2[d*64 + c];
        else if (c < 256) v = Whh[(c-64)*64 + d];
        else              v = root[d*64 + (c-256)];
        BsmT[t] = v;
    }
    if (t < 12288) { int k = t / 192; WihT[t] = Wih[(t - k*192)*64 + k]; }  // WihT[k][g]
    if (t < NE) {
        atomicAdd(&deg[ei[NE + t]], 1);   // in-degree (dst) for mean aggr
        atomicAdd(&cnt[ei[t]], 1);        // out-degree (src) for edge sort
    }
}

// ---------------- exclusive scan of cnt[4096] -> offs[4097] (1 block) ----------------
__global__ __launch_bounds__(256) void scan_kernel(const int* __restrict__ cnt,
                                                   int* __restrict__ offs)
{
    __shared__ int ps[256];
    int t = threadIdx.x;
    int base = t*16;
    int loc[16];
    int s = 0;
    #pragma unroll
    for (int i = 0; i < 16; ++i) { loc[i] = s; s += cnt[base+i]; }
    ps[t] = s; __syncthreads();
    for (int off = 1; off < 256; off <<= 1) {
        int v = 0;
        if (t >= off) v = ps[t-off];
        __syncthreads();
        if (t >= off) ps[t] += v;
        __syncthreads();
    }
    int pre = (t == 0) ? 0 : ps[t-1];
    #pragma unroll
    for (int i = 0; i < 16; ++i) offs[base+i] = pre + loc[i];
    if (t == 255) offs[NN] = pre + s;
}

// ---------------- scatter: build src-sorted edge arrays ----------------
__global__ __launch_bounds__(256) void scatter_kernel(
    const int* __restrict__ ei, const int* __restrict__ offs,
    int* __restrict__ cnt,  // consumed as cursor via atomicSub
    int* __restrict__ srcs, int* __restrict__ dsts, int* __restrict__ perm)
{
    int e = blockIdx.x*256 + threadIdx.x;
    if (e >= NE) return;
    int s = ei[e], d = ei[NE + e];
    int old = atomicSub(&cnt[s], 1);
    int pos = offs[s] + old - 1;
    srcs[pos] = s; dsts[pos] = d; perm[pos] = e;
}

// ---------------- permute he into sorted-edge order (one-time) ----------------
__global__ __launch_bounds__(256) void heperm_kernel(
    const float* __restrict__ he, const int* __restrict__ perm,
    float* __restrict__ he_s)
{
    int t = blockIdx.x*256 + threadIdx.x;   // NE*64 threads
    int pos = t >> 6, f = t & 63;
    he_s[t] = he[(size_t)perm[pos]*64 + f];
}

// ---------------- inv_deg + per-graph node ranges ----------------
__global__ __launch_bounds__(256) void inv_range_kernel(
    const int* __restrict__ deg, const int* __restrict__ batch,
    float* __restrict__ inv_deg, int* __restrict__ gstart, int* __restrict__ gend)
{
    int n = blockIdx.x*256 + threadIdx.x;
    if (n >= NN) return;
    inv_deg[n] = 1.f / fmaxf((float)deg[n], 1.f);
    int b  = batch[n];
    int bp = (n == 0)    ? -1 : batch[n-1];
    int bn = (n == NN-1) ? BG : batch[n+1];
    for (int g = bp+1; g <= b; ++g) gstart[g] = n;
    for (int g = b;   g <  bn; ++g) gend[g]   = n+1;
    if (n == 0)    for (int g = 0;   g < b;  ++g) gend[g]   = 0;
    if (n == NN-1) for (int g = b+1; g < BG; ++g) gstart[g] = NN;
}

// ---------------- per-iter small GEMM: Csm[4096][320] = h @ BsmT^T ----------------
// cols: [bias(be2):64][gh r,z,n:192][mroot:64]
__global__ __launch_bounds__(256) void csm_gemm(
    const float* __restrict__ h, const float* __restrict__ BsmT,
    float* __restrict__ Csm)
{
    __shared__ float ht[8][64];
    int t = threadIdx.x;
    int n0 = blockIdx.x * 8;
    #pragma unroll
    for (int i = 0; i < 2; ++i) {       // 512 floats, 256 threads -> 2 each
        int idx = t + i*256;
        ht[idx>>6][idx&63] = h[(size_t)n0*64 + idx];
    }
    __syncthreads();
    for (int idx = t; idx < 8*320; idx += 256) {
        int r = idx / 320, c = idx - r*320;
        const float* bt = BsmT + (size_t)c*64;
        const float* hr = ht[r];
        float s = 0.f;
        #pragma unroll 8
        for (int d = 0; d < 64; d += 4) {
            float4 a = *(const float4*)(hr + d);
            float4 b = *(const float4*)(bt + d);
            s += a.x*b.x + a.y*b.y + a.z*b.z + a.w*b.w;
        }
        Csm[(size_t)(n0+r)*320 + c] = s;
    }
}

// ---------------- fused: 16-node x 16-k G tile in LDS + edge contraction ----------------
// grid (256 node-tiles, 4 k-chunks) x 256 thr. Thread owns 4 consecutive cols
// of the 1024-col (16k x 64f) tile: acc[16][4], A broadcast via readlane.
// Edge phase: wave-per-edge, lane=f, serial k-loop, 1 atomic/(edge,f,chunk).
__global__ __launch_bounds__(256) void fused_msg(
    const float* __restrict__ h, const float* __restrict__ Bp2,
    const float* __restrict__ he_s, const float* __restrict__ Csm,
    const int* __restrict__ offs, const int* __restrict__ srcs,
    const int* __restrict__ dsts, float* __restrict__ agg)
{
    __shared__ float G[16*1024];   // 64 KB: G[n][k_local*64+f]
    int t = threadIdx.x;
    int n0  = blockIdx.x * 16;
    int kc0 = blockIdx.y * 16;     // k-chunk base
    int lane = t & 63, w = t >> 6;

    // A tile in registers: h_reg[n] = h[n0+n][lane] (per-wave copy, L1-served)
    float h_reg[16];
    #pragma unroll
    for (int n = 0; n < 16; ++n) h_reg[n] = h[(size_t)(n0+n)*64 + lane];

    // GEMM: thread owns cols c = t*4..t*4+3 of [16k x 64f] chunk
    float4 acc[16];
    #pragma unroll
    for (int n = 0; n < 16; ++n) acc[n] = make_float4(0.f,0.f,0.f,0.f);

    const float* bp = Bp2 + (size_t)kc0*64 + t*4;
    #pragma unroll 4
    for (int d = 0; d < 64; ++d) {
        float4 b = *(const float4*)(bp + (size_t)d*4096);
        #pragma unroll
        for (int n = 0; n < 16; ++n) {
            float av = rl(h_reg[n], d);
            acc[n].x += av*b.x; acc[n].y += av*b.y;
            acc[n].z += av*b.z; acc[n].w += av*b.w;
        }
    }
    #pragma unroll
    for (int n = 0; n < 16; ++n)
        *(float4*)&G[n*1024 + t*4] = acc[n];
    __syncthreads();

    // Edge phase
    int est  = offs[n0];
    int eend = offs[n0+16];
    bool c0 = (blockIdx.y == 0);
    for (int e = est + w; e < eend; e += 4) {
        int src = srcs[e], dst = dsts[e];
        int base = (src - n0) * 1024;
        float hv = he_s[(size_t)e*64 + kc0 + (lane & 15)];   // lanes 0..15 hold k
        float m0 = c0 ? Csm[(size_t)src*320 + lane] : 0.f;   // bias[src,f] once
        float m1 = 0.f, m2 = 0.f, m3 = 0.f;
        #pragma unroll
        for (int k = 0; k < 16; k += 4) {
            m0 += rl(hv, k+0) * G[base + (k+0)*64 + lane];
            m1 += rl(hv, k+1) * G[base + (k+1)*64 + lane];
            m2 += rl(hv, k+2) * G[base + (k+2)*64 + lane];
            m3 += rl(hv, k+3) * G[base + (k+3)*64 + lane];
        }
        atomicAdd(&agg[(size_t)dst*64 + lane], (m0+m1)+(m2+m3));
    }
}

// ---------------- node kernel: m -> gi GEMM -> GRU (in-place h); zeros agg ----
__global__ __launch_bounds__(256) void node_kernel(
    const float* __restrict__ Csm, float* __restrict__ agg,
    const float* __restrict__ inv_deg, const float* __restrict__ conv_b,
    const float* __restrict__ WihT, const float* __restrict__ bih,
    const float* __restrict__ bhh, float* __restrict__ h)
{
    __shared__ float mT[64][18];    // m transposed [d][node]; stride 18 (72 B, 8-aligned)
    int t = threadIdx.x;
    int n0 = blockIdx.x * 16;
    #pragma unroll
    for (int i = 0; i < 4; ++i) {   // m = lrelu(agg*inv + mroot + conv_b); zero agg
        int idx = t + i*256;
        int n = idx >> 6, dd = idx & 63;
        int gn = n0 + n;
        float av = agg[(size_t)gn*64 + dd];
        agg[(size_t)gn*64 + dd] = 0.f;   // ready for next iteration
        float mr = Csm[(size_t)gn*320 + 256 + dd];
        mT[dd][n] = lrelu(av*inv_deg[gn] + mr + conv_b[dd]);
    }
    __syncthreads();

    int tx = t & 31, ty = t >> 5;   // tx: gate pair, ty: node pair
    float acc[2][2][3] = {};
    #pragma unroll 4
    for (int k = 0; k < 64; ++k) {  // WihT rows from L1 (8-way in-block reuse)
        float2 a  = *(float2*)&mT[k][ty*2];
        const float* wk = WihT + k*192;
        float2 br = *(const float2*)(wk + tx*2);
        float2 bz = *(const float2*)(wk + 64 + tx*2);
        float2 bn = *(const float2*)(wk + 128 + tx*2);
        acc[0][0][0] += a.x*br.x; acc[0][1][0] += a.x*br.y;
        acc[1][0][0] += a.y*br.x; acc[1][1][0] += a.y*br.y;
        acc[0][0][1] += a.x*bz.x; acc[0][1][1] += a.x*bz.y;
        acc[1][0][1] += a.y*bz.x; acc[1][1][1] += a.y*bz.y;
        acc[0][0][2] += a.x*bn.x; acc[0][1][2] += a.x*bn.y;
        acc[1][0][2] += a.y*bn.x; acc[1][1][2] += a.y*bn.y;
    }
    #pragma unroll
    for (int i = 0; i < 2; ++i) {
        int n = n0 + ty*2 + i;
        const float* Cn = Csm + (size_t)n*320;
        #pragma unroll
        for (int j = 0; j < 2; ++j) {
            int g = tx*2 + j;
            float r  = sigm(acc[i][j][0] + bih[g]     + Cn[64  + g] + bhh[g]);
            float z  = sigm(acc[i][j][1] + bih[64+g]  + Cn[128 + g] + bhh[64+g]);
            float nn = tanhf(acc[i][j][2] + bih[128+g] + r*(Cn[192 + g] + bhh[128+g]));
            float ho = h[(size_t)n*64 + g];
            h[(size_t)n*64 + g] = (1.f - z)*nn + z*ho;
        }
    }
}

// ---------------- finale ----------------
__device__ __forceinline__ float q_val(const float* lbih, const float* lbhh, int g)
{
    float gi = lbih[g]     + lbhh[g];
    float gg = lbih[128+g] + lbhh[128+g];
    float go = lbih[192+g] + lbhh[192+g];
    return sigm(go)*tanhf(sigm(gi)*tanhf(gg));   // hl0=cl0=q_star0=0
}

__global__ __launch_bounds__(256) void e_kernel(
    const float* __restrict__ h, const float* __restrict__ lbih,
    const float* __restrict__ lbhh, float* __restrict__ e)
{
    __shared__ float qs[64];
    int t = threadIdx.x;
    if (t < 64) qs[t] = q_val(lbih, lbhh, t);
    __syncthreads();
    int w = t >> 6, f = t & 63;
    int n = blockIdx.x*4 + w;
    float p = h[(size_t)n*64 + f]*qs[f];
    #pragma unroll
    for (int off = 32; off; off >>= 1) p += __shfl_xor(p, off);
    if (f == 0) e[n] = p;
}

__global__ __launch_bounds__(1024) void pool_kernel(
    const float* __restrict__ h, float* __restrict__ e,
    const int* __restrict__ gstart, const int* __restrict__ gend,
    const float* __restrict__ lbih, const float* __restrict__ lbhh,
    const float* __restrict__ Wout, const float* __restrict__ bout,
    float* __restrict__ out)
{
    __shared__ float red[1024];
    __shared__ float rp[64];
    __shared__ float sval;
    int g = blockIdx.x, t = threadIdx.x;
    int s = gstart[g], en = gend[g];

    float mx = -1e30f;
    for (int n = s+t; n < en; n += 1024) mx = fmaxf(mx, e[n]);
    red[t] = mx; __syncthreads();
    for (int st = 512; st; st >>= 1) { if (t < st) red[t] = fmaxf(red[t], red[t+st]); __syncthreads(); }
    if (t == 0) sval = red[0];
    __syncthreads();
    float lmx = sval;
    __syncthreads();

    float sm = 0.f;
    for (int n = s+t; n < en; n += 1024) { float a = expf(e[n]-lmx); e[n] = a; sm += a; }
    red[t] = sm; __syncthreads();
    for (int st = 512; st; st >>= 1) { if (t < st) red[t] += red[t+st]; __syncthreads(); }
    if (t == 0) sval = (red[0] > 0.f) ? 1.f/red[0] : 0.f;
    __syncthreads();
    float inv_asum = sval;
    __syncthreads();

    int w = t >> 6, f = t & 63;
    float racc = 0.f;
    for (int n = s+w; n < en; n += 16) racc += e[n]*h[(size_t)n*64 + f];
    red[t] = racc; __syncthreads();
    if (w == 0) {
        float a = 0.f;
        #pragma unroll
        for (int i = 0; i < 16; ++i) a += red[i*64 + f];
        rp[f] = a*inv_asum;
    }
    __syncthreads();

    if (t < 64) {
        float qv = q_val(lbih, lbhh, t);
        float p0 = qv*Wout[t*2]   + rp[t]*Wout[(64+t)*2];
        float p1 = qv*Wout[t*2+1] + rp[t]*Wout[(64+t)*2+1];
        #pragma unroll
        for (int off = 32; off; off >>= 1) { p0 += __shfl_xor(p0, off); p1 += __shfl_xor(p1, off); }
        if (t == 0) { out[g*2] = p0 + bout[0]; out[g*2+1] = p1 + bout[1]; }
    }
}

extern "C" void kernel_launch(void* const* d_in, const int* in_sizes, int n_in,
                              void* d_out, int out_size, void* d_ws, size_t ws_size,
                              hipStream_t stream)
{
    const float* x      = (const float*)d_in[0];
    const float* ea     = (const float*)d_in[1];
    const int*   ei     = (const int*)  d_in[2];
    const int*   batch  = (const int*)  d_in[3];
    const float* W0     = (const float*)d_in[4];
    const float* b0     = (const float*)d_in[5];
    const float* We1    = (const float*)d_in[6];
    const float* be1    = (const float*)d_in[7];
    const float* We2    = (const float*)d_in[8];
    const float* be2    = (const float*)d_in[9];
    const float* root   = (const float*)d_in[10];
    const float* conv_b = (const float*)d_in[11];
    const float* Wih    = (const float*)d_in[12];
    const float* Whh    = (const float*)d_in[13];
    const float* bih    = (const float*)d_in[14];
    const float* bhh    = (const float*)d_in[15];
    const float* lbih   = (const float*)d_in[18];
    const float* lbhh   = (const float*)d_in[19];
    const float* Wout   = (const float*)d_in[20];
    const float* bout   = (const float*)d_in[21];
    float* out = (float*)d_out;

    float* W = (float*)d_ws;
    size_t off = 0;
    float* h       = W + off; off += (size_t)NN*64;
    float* he      = W + off; off += (size_t)NE*64;
    float* he_s    = W + off; off += (size_t)NE*64;
    float* agg     = W + off; off += (size_t)NN*64;
    float* Bp2     = W + off; off += (size_t)64*4096;
    float* BsmT    = W + off; off += 320*64;
    float* Csm     = W + off; off += (size_t)NN*320;
    float* WihT    = W + off; off += 12288;
    float* inv_deg = W + off; off += NN;
    float* e       = W + off; off += NN;
    int*   deg     = (int*)(W + off); off += NN;   // deg+cnt contiguous: one memset
    int*   cnt     = (int*)(W + off); off += NN;
    int*   offs    = (int*)(W + off); off += NN+1;
    int*   srcs    = (int*)(W + off); off += NE;
    int*   dsts    = (int*)(W + off); off += NE;
    int*   perm    = (int*)(W + off); off += NE;
    int*   gstart  = (int*)(W + off); off += BG;
    int*   gend    = (int*)(W + off); off += BG;

    hipMemsetAsync(deg, 0, 2*NN*sizeof(int), stream);
    setup_kernel<<<4096, 256, 0, stream>>>(x, ea, ei, W0, b0, We1, be1, We2, be2,
                                           root, Whh, Wih, Bp2, BsmT, WihT,
                                           h, he, deg, cnt, agg);
    scan_kernel<<<1, 256, 0, stream>>>(cnt, offs);
    scatter_kernel<<<64, 256, 0, stream>>>(ei, offs, cnt, srcs, dsts, perm);
    heperm_kernel<<<4096, 256, 0, stream>>>(he, perm, he_s);
    inv_range_kernel<<<16, 256, 0, stream>>>(deg, batch, inv_deg, gstart, gend);

    for (int it = 0; it < 6; ++it) {
        csm_gemm<<<NN/8, 256, 0, stream>>>(h, BsmT, Csm);
        fused_msg<<<dim3(NN/16, 4), 256, 0, stream>>>(h, Bp2, he_s, Csm,
                                                      offs, srcs, dsts, agg);
        node_kernel<<<NN/16, 256, 0, stream>>>(Csm, agg, inv_deg, conv_b,
                                               WihT, bih, bhh, h);
    }

    e_kernel<<<NN/4, 256, 0, stream>>>(h, lbih, lbhh, e);
    pool_kernel<<<BG, 1024, 0, stream>>>(h, e, gstart, gend, lbih, lbhh, Wout, bout, out);
}